// Round 11
// baseline (268.364 us; speedup 1.0000x reference)
//
#include <hip/hip_runtime.h>
#include <hip/hip_bf16.h>

// BinaryLinear: out[131072,256] = x[131072,256] @ (sign(W)*scale)[256,256]^T + bias
// R7 post-mortem: VGPR=144=breg+acc exactly -> compiler sank the prefetch loads
// (serial load->wait->cvt->mfma), and persistent grid gave 1 wave/SIMD (no TLP).
// R8: 1024 blocks x 8 tiles (2 waves/SIMD resident via launch_bounds(256,2)),
// batched 16-load tile read pinned with sched_barrier(0) before cvt phase.

typedef __bf16 bf16_t;
typedef __attribute__((ext_vector_type(8))) __bf16 bf16x8;  // MFMA A/B fragment (4 VGPR)
typedef __attribute__((ext_vector_type(4))) float f32x4;    // MFMA C/D fragment

#define MROWS 131072
#define NDIM 256
#define KDIM 256
#define TROWS 16
#define NT (MROWS / TROWS)   // 8192 row-tiles
#define TILES 8              // tiles per block (contiguous 128-row strip)
#define GRID (NT / TILES)    // 1024 blocks

// ---- Kernel 1: wb[o][i] = bf16(sign(W[o][i]))  (+1/-1/0, exact in bf16) ----
__global__ __launch_bounds__(256) void prep_w_kernel(const float* __restrict__ W,
                                                     bf16_t* __restrict__ wb) {
    int idx = blockIdx.x * 256 + threadIdx.x;   // 0 .. 65535
    float w = W[idx];
    wb[idx] = (bf16_t)((w > 0.0f) ? 1.0f : ((w < 0.0f) ? -1.0f : 0.0f));
}

__device__ inline bf16x8 cvt8(f32x4 lo, f32x4 hi) {
    bf16x8 r;
    r[0] = (bf16_t)lo.x; r[1] = (bf16_t)lo.y; r[2] = (bf16_t)lo.z; r[3] = (bf16_t)lo.w;
    r[4] = (bf16_t)hi.x; r[5] = (bf16_t)hi.y; r[6] = (bf16_t)hi.z; r[7] = (bf16_t)hi.w;
    return r;
}

// ---- Kernel 2: GEMM, B-in-registers, 8 tiles/block, burst-load x ----
// Block: 256 thr (4 waves). Wave w owns cols [w*64, w*64+64) of its 8 tiles.
// Per tile: issue all 16 x-loads -> sched_barrier -> cvt -> 32 MFMA -> 16 stores.
// No LDS, no __syncthreads anywhere. TLP (8 waves/CU) hides the load waits.
__global__ __launch_bounds__(256, 2) void bin_gemm_kernel(
        const float* __restrict__ x,
        const bf16_t* __restrict__ wb,
        const float* __restrict__ scale,
        const float* __restrict__ bias,
        float* __restrict__ out) {
    const int tid  = threadIdx.x;
    const int lane = tid & 63;
    const int wave = tid >> 6;
    const int lrow = lane & 15;      // frag row (A) / col (B,C)
    const int lk   = lane >> 4;      // k-group
    const int cb   = wave * 64;      // this wave's output-column base

    // ---- persistent B for this block: 4 col-frags x 8 k-steps = 128 VGPR ----
    bf16x8 breg[4][8];
    #pragma unroll
    for (int ni = 0; ni < 4; ++ni) {
        const bf16_t* pb = wb + (size_t)(cb + ni * 16 + lrow) * KDIM + lk * 8;
        #pragma unroll
        for (int ks = 0; ks < 8; ++ks)
            breg[ni][ks] = *reinterpret_cast<const bf16x8*>(pb + ks * 32);
    }
    float sc[4], bi[4];
    #pragma unroll
    for (int ni = 0; ni < 4; ++ni) {
        sc[ni] = scale[cb + ni * 16 + lrow];
        bi[ni] = bias[cb + ni * 16 + lrow];
    }

    const int t0 = blockIdx.x * TILES;
    for (int ti = 0; ti < TILES; ++ti) {
        const int t = t0 + ti;
        const float* px = x + ((size_t)t * TROWS + lrow) * KDIM + lk * 8;

        // ---- burst: issue all 16 loads for this tile ----
        f32x4 xlo[8], xhi[8];
        #pragma unroll
        for (int ks = 0; ks < 8; ++ks) {
            xlo[ks] = *reinterpret_cast<const f32x4*>(px + ks * 32);
            xhi[ks] = *reinterpret_cast<const f32x4*>(px + ks * 32 + 4);
        }
        __builtin_amdgcn_sched_barrier(0);   // keep the 16 loads batched ahead of cvt

        bf16x8 a[8];
        #pragma unroll
        for (int ks = 0; ks < 8; ++ks) a[ks] = cvt8(xlo[ks], xhi[ks]);

        // 32 MFMA: 4 independent acc chains (ni)
        f32x4 acc[4] = {};
        #pragma unroll
        for (int ks = 0; ks < 8; ++ks)
            #pragma unroll
            for (int ni = 0; ni < 4; ++ni)
                acc[ni] = __builtin_amdgcn_mfma_f32_16x16x32_bf16(
                              a[ks], breg[ni][ks], acc[ni], 0, 0, 0);

        // epilogue: out = acc * scale + bias (f32)
        float* po = out + ((size_t)t * TROWS + lk * 4) * NDIM;
        #pragma unroll
        for (int ni = 0; ni < 4; ++ni) {
            int col = cb + ni * 16 + lrow;
            #pragma unroll
            for (int r = 0; r < 4; ++r)   // C/D: row=(lane>>4)*4+r, col=lane&15
                po[(size_t)r * NDIM + col] = acc[ni][r] * sc[ni] + bi[ni];
        }
    }
}

extern "C" void kernel_launch(void* const* d_in, const int* in_sizes, int n_in,
                              void* d_out, int out_size, void* d_ws, size_t ws_size,
                              hipStream_t stream) {
    const float* x     = (const float*)d_in[0];
    const float* W     = (const float*)d_in[1];
    const float* scale = (const float*)d_in[2];
    const float* bias  = (const float*)d_in[3];
    float*       out   = (float*)d_out;
    bf16_t*      wb    = (bf16_t*)d_ws;        // 256*256*2 = 128 KiB scratch

    prep_w_kernel<<<NDIM * KDIM / 256, 256, 0, stream>>>(W, wb);
    bin_gemm_kernel<<<GRID, 256, 0, stream>>>(x, wb, scale, bias, out);
}

// Round 13
// 245.610 us; speedup vs baseline: 1.0926x; 1.0926x over previous
//
#include <hip/hip_runtime.h>
#include <hip/hip_bf16.h>

// BinaryLinear: out[131072,256] = x[131072,256] @ (sign(W)*scale)[256,256]^T + bias
// R8 post-mortem: register-path x loads get serialized by the allocator (3rd time).
// R9: x staged via __builtin_amdgcn_global_load_lds (async DMA - cannot be sunk),
// double-buffered 16-row tiles, raw s_barrier + counted asm vmcnt(4) (never 0
// mid-loop, T3/T4), source-side XOR swizzle so ds_read_b128 is conflict-free (T2).
// B stays persistent in registers (breg 128 VGPR, proven held in R7).

typedef __bf16 bf16_t;
typedef __attribute__((ext_vector_type(8))) __bf16 bf16x8;  // MFMA A/B fragment
typedef __attribute__((ext_vector_type(4))) float f32x4;    // MFMA C/D fragment

#define MROWS 131072
#define NDIM 256
#define KDIM 256
#define TROWS 16
#define TILES 8
#define GRID (MROWS / (TROWS * TILES))   // 1024 blocks

// ---- Kernel 1: wb[o][i] = bf16(sign(W[o][i]))  (+1/-1/0, exact in bf16) ----
__global__ __launch_bounds__(256) void prep_w_kernel(const float* __restrict__ W,
                                                     bf16_t* __restrict__ wb) {
    int idx = blockIdx.x * 256 + threadIdx.x;
    float w = W[idx];
    wb[idx] = (bf16_t)((w > 0.0f) ? 1.0f : ((w < 0.0f) ? -1.0f : 0.0f));
}

__device__ inline bf16x8 cvt8(f32x4 lo, f32x4 hi) {
    bf16x8 r;
    r[0] = (bf16_t)lo.x; r[1] = (bf16_t)lo.y; r[2] = (bf16_t)lo.z; r[3] = (bf16_t)lo.w;
    r[4] = (bf16_t)hi.x; r[5] = (bf16_t)hi.y; r[6] = (bf16_t)hi.z; r[7] = (bf16_t)hi.w;
    return r;
}

// Stage one 16x256-f32 tile (16 KiB, contiguous) into LDS via async DMA.
// LDS slot (r, c') holds x slot (r, c'^(r&7)): swizzle applied on the GLOBAL
// source address (per-lane), DMA dest stays linear (wave-uniform base + lane*16).
__device__ inline void stage_tile(char* dst, const float* xt, int tid) {
    const char* src = (const char*)xt;
    #pragma unroll
    for (int p = 0; p < 4; ++p) {
        int s = p * 256 + tid;          // linear dest slot (16 B units), 0..1023
        int r = s >> 6;                 // row (64 slots per 1 KiB row)
        int c = s & 63;
        __builtin_amdgcn_global_load_lds(
            (const __attribute__((address_space(1))) void*)(src + r * 1024 + ((c ^ (r & 7)) * 16)),
            (__attribute__((address_space(3))) void*)(dst + p * 4096 + (tid & 192) * 16),
            16, 0, 0);
    }
}

// ---- Kernel 2: GEMM. breg in VGPRs, x via DMA-dbuf LDS, counted vmcnt. ----
__global__ __launch_bounds__(256, 2) void bin_gemm_kernel(
        const float* __restrict__ x,
        const bf16_t* __restrict__ wb,
        const float* __restrict__ scale,
        const float* __restrict__ bias,
        float* __restrict__ out) {
    __shared__ __align__(16) char xlds[2][16384];   // 32 KiB double buffer

    const int tid  = threadIdx.x;
    const int lane = tid & 63;
    const int wave = tid >> 6;
    const int lrow = lane & 15;      // frag row (A) / col (B,C)
    const int lk   = lane >> 4;      // k-group
    const int cb   = wave * 64;      // this wave's output-column base

    // persistent B: 4 col-frags x 8 k-steps = 128 VGPR
    bf16x8 breg[4][8];
    #pragma unroll
    for (int ni = 0; ni < 4; ++ni) {
        const bf16_t* pb = wb + (size_t)(cb + ni * 16 + lrow) * KDIM + lk * 8;
        #pragma unroll
        for (int ks = 0; ks < 8; ++ks)
            breg[ni][ks] = *reinterpret_cast<const bf16x8*>(pb + ks * 32);
    }
    float sc[4], bi[4];
    #pragma unroll
    for (int ni = 0; ni < 4; ++ni) {
        sc[ni] = scale[cb + ni * 16 + lrow];
        bi[ni] = bias[cb + ni * 16 + lrow];
    }

    const int t0 = blockIdx.x * TILES;
    stage_tile(xlds[0], x + (size_t)t0 * TROWS * KDIM, tid);   // prologue: tile 0

    const int swz = lrow & 7;
    for (int ti = 0; ti < TILES; ++ti) {
        __builtin_amdgcn_s_barrier();   // WAR: all waves done reading buf[(ti+1)&1]
        if (ti + 1 < TILES)
            stage_tile(xlds[(ti + 1) & 1], x + (size_t)(t0 + ti + 1) * TROWS * KDIM, tid);
        // Wait for THIS tile's DMAs; keep next tile's 4 DMAs in flight (never 0 mid-loop).
        if (ti + 1 < TILES) asm volatile("s_waitcnt vmcnt(4)" ::: "memory");
        else                asm volatile("s_waitcnt vmcnt(0)" ::: "memory");
        __builtin_amdgcn_sched_barrier(0);
        __builtin_amdgcn_s_barrier();   // RAW: every wave's DMA for tile ti landed

        const char* cur = xlds[ti & 1] + lrow * 1024;
        f32x4 acc[4] = {};
        #pragma unroll
        for (int ks = 0; ks < 8; ++ks) {
            int c0 = ks * 8 + lk * 2;
            f32x4 lo = *reinterpret_cast<const f32x4*>(cur + ((c0 ^ swz) * 16));
            f32x4 hi = *reinterpret_cast<const f32x4*>(cur + (((c0 + 1) ^ swz) * 16));
            bf16x8 a = cvt8(lo, hi);
            #pragma unroll
            for (int ni = 0; ni < 4; ++ni)
                acc[ni] = __builtin_amdgcn_mfma_f32_16x16x32_bf16(
                              a, breg[ni][ks], acc[ni], 0, 0, 0);
        }

        float* po = out + ((size_t)(t0 + ti) * TROWS + lk * 4) * NDIM;
        #pragma unroll
        for (int ni = 0; ni < 4; ++ni) {
            int col = cb + ni * 16 + lrow;
            #pragma unroll
            for (int r = 0; r < 4; ++r)   // C/D: row=(lane>>4)*4+r, col=lane&15
                po[(size_t)r * NDIM + col] = acc[ni][r] * sc[ni] + bi[ni];
        }
    }
}

extern "C" void kernel_launch(void* const* d_in, const int* in_sizes, int n_in,
                              void* d_out, int out_size, void* d_ws, size_t ws_size,
                              hipStream_t stream) {
    const float* x     = (const float*)d_in[0];
    const float* W     = (const float*)d_in[1];
    const float* scale = (const float*)d_in[2];
    const float* bias  = (const float*)d_in[3];
    float*       out   = (float*)d_out;
    bf16_t*      wb    = (bf16_t*)d_ws;        // 256*256*2 = 128 KiB scratch

    prep_w_kernel<<<NDIM * KDIM / 256, 256, 0, stream>>>(W, wb);
    bin_gemm_kernel<<<GRID, 256, 0, stream>>>(x, wb, scale, bias, out);
}